// Round 10
// baseline (1688.432 us; speedup 1.0000x reference)
//
#include <hip/hip_runtime.h>
#include <math.h>

#define TPB 256
static inline int cdiv(int a, int b) { return (a + b - 1) / b; }

typedef __attribute__((ext_vector_type(8))) short short8;
typedef __attribute__((ext_vector_type(4))) float floatx4;

__device__ __forceinline__ float bf2f(ushort u) {
    union { unsigned int u; float f; } v; v.u = ((unsigned int)u) << 16; return v.f;
}
__device__ __forceinline__ ushort f2bf(float f) {
    union { float f; unsigned int u; } v; v.f = f;
    unsigned int r = (v.u + 0x7FFFu + ((v.u >> 16) & 1u)) >> 16;
    return (ushort)r;
}

// Concatenated pyramid layout: rows [0,16384) l0(H=64), [16384,20480) l1(H=32),
// [20480,21504) l2(H=16), [21504,21760) l3(H=8), [21760,21824) l4(H=4).
#define CONC_ROWS 21824
__device__ __forceinline__ void lvl_of(int row, int& lvl, int& base) {
    lvl = 0; base = 0;
    if (row >= 16384) { lvl = 1; base = 16384; }
    if (row >= 20480) { lvl = 2; base = 20480; }
    if (row >= 21504) { lvl = 3; base = 21504; }
    if (row >= 21760) { lvl = 4; base = 21760; }
}
__constant__ int LOFFc[5] = {0, 36864, 46080, 48384, 48960};

// B slab per tap: [3ks][4g][96n][8j] = 9216 ushorts = 18432 B = 1152 x 16B
#define BSLAB 9216

// async global->LDS 16B DMA
__device__ __forceinline__ void gld_lds16(const ushort* g, ushort* l) {
    __builtin_amdgcn_global_load_lds(
        (const __attribute__((address_space(1))) unsigned int*)g,
        (__attribute__((address_space(3))) unsigned int*)l, 16, 0, 0);
}

// ---------------------------------------------------------------------------
// Merged weight packing: one kernel, range-dispatched.
// pw:  [0, 221184)           24 x [3ks][4g][96n][8j]
// tw8: [221184, 884736)      8 tower convs
// ro:  [884736, 967680)      reg out (Ntot=96, CO=36)
// co:  [967680, 1714176)     cls out [9nb][9tap][3ks][4g][96n][8j]
// lat: [1714176, 1790976)    5 laterals
// ---------------------------------------------------------------------------
__global__ void pack_all_k(const float* __restrict__ pw, const float* __restrict__ rw,
                           const float* __restrict__ cw, const float* __restrict__ row_,
                           const float* __restrict__ cow,
                           const float* __restrict__ w3, const float* __restrict__ w4,
                           const float* __restrict__ w5, const float* __restrict__ w6,
                           const float* __restrict__ w7,
                           ushort* __restrict__ BP_PW, ushort* __restrict__ BP_TW,
                           ushort* __restrict__ BP_RO, ushort* __restrict__ BP_CO,
                           ushort* __restrict__ BP_LAT) {
    int gid = blockIdx.x * blockDim.x + threadIdx.x;
    if (gid < 221184) {
        int idx = gid;
        int cid = idx / BSLAB; int r = idx - cid * BSLAB;
        int j = r & 7; int t = r >> 3;
        int n = t % 96; t /= 96;
        int g = t & 3; int ks = t >> 2;
        int ci = ks * 32 + g * 8 + j;
        float v = (ci < 88 && n < 88) ? pw[(size_t)cid * 7744 + n * 88 + ci] : 0.f;
        BP_PW[idx] = f2bf(v);
    } else if (gid < 884736) {
        int idx = gid - 221184;
        int i = idx / 82944; int r = idx - i * 82944;
        const float* w = (i < 4) ? rw + (size_t)i * 69696 : cw + (size_t)(i - 4) * 69696;
        int j = r & 7; int t = r >> 3;
        int n = t % 96; t /= 96;
        int g = t & 3; t >>= 2;
        int ks = t % 3; int tap = t / 3;
        int ci = ks * 32 + g * 8 + j;
        float v = (ci < 88 && n < 88) ? w[((size_t)n * 88 + ci) * 9 + tap] : 0.f;
        BP_TW[idx] = f2bf(v);
    } else if (gid < 967680) {
        int idx = gid - 884736;
        int j = idx & 7; int t = idx >> 3;
        int n = t % 96; t /= 96;
        int g = t & 3; t >>= 2;
        int ks = t % 3; int tap = t / 3;
        int ci = ks * 32 + g * 8 + j;
        float v = (ci < 88 && n < 36) ? row_[((size_t)n * 88 + ci) * 9 + tap] : 0.f;
        BP_RO[idx] = f2bf(v);
    } else if (gid < 1714176) {
        int idx = gid - 967680;
        int j = idx & 7; int t = idx >> 3;
        int n = t % 96; t /= 96;
        int g = t & 3; t >>= 2;
        int ks = t % 3; t /= 3;
        int tap = t % 9; int nb = t / 9;
        int ci = ks * 32 + g * 8 + j;
        int co = nb * 96 + n;
        float v = (ci < 88 && co < 810) ? cow[((size_t)co * 88 + ci) * 9 + tap] : 0.f;
        BP_CO[idx] = f2bf(v);
    } else if (gid < 1790976) {
        int idx = gid - 1714176;
        int l, off;
        if (idx < 6144)       { l = 0; off = 0; }
        else if (idx < 15360) { l = 1; off = 6144; }
        else if (idx < 27648) { l = 2; off = 15360; }
        else if (idx < 46080) { l = 3; off = 27648; }
        else                  { l = 4; off = 46080; }
        const float* w = l == 0 ? w3 : l == 1 ? w4 : l == 2 ? w5 : l == 3 ? w6 : w7;
        const int cins[5] = {40, 80, 112, 192, 320};
        int Cin = cins[l];
        int r = idx - off;
        int j = r & 7; int t = r >> 3;
        int n = t % 96; t /= 96;
        int g = t & 3; int ks = t >> 2;
        int ci = ks * 32 + g * 8 + j;
        float v = (ci < Cin && n < 88) ? w[(size_t)n * Cin + ci] : 0.f;
        BP_LAT[idx] = f2bf(v);
    }
}

// ---------------------------------------------------------------------------
// Device-scope grid barrier. Each counter used exactly once per launch
// (zeroed by hipMemsetAsync before the kernel).
// ---------------------------------------------------------------------------
__device__ __forceinline__ void gbar(int* cnt, int target) {
    __syncthreads();
    if (threadIdx.x == 0) {
        __threadfence();   // publish this block's global writes (agent scope)
        __hip_atomic_fetch_add(cnt, 1, __ATOMIC_RELEASE, __HIP_MEMORY_SCOPE_AGENT);
        while (__hip_atomic_load(cnt, __ATOMIC_ACQUIRE, __HIP_MEMORY_SCOPE_AGENT) < target)
            __builtin_amdgcn_s_sleep(2);
        __threadfence();   // acquire: invalidate caches before consuming
    }
    __syncthreads();
}

// ---------------------------------------------------------------------------
// Lateral conv work unit (64 pixels): NCHW fp32 -> NHWC96 bf16, no act.
// ---------------------------------------------------------------------------
__device__ void lateral_work(const float* __restrict__ x, const ushort* __restrict__ Bp,
                             const float* __restrict__ bias, ushort* __restrict__ out,
                             int Cin, int KS, int logHH, int blk, ushort* As) {
    int tid = threadIdx.x;
    int m0 = blk * 64;
    int lane = tid & 63, l15 = lane & 15, g = (lane >> 4) & 3;
    int wave = tid >> 6, wm = wave & 1, wn = wave >> 1;
    floatx4 acc[2][3];
#pragma unroll
    for (int a = 0; a < 2; ++a)
#pragma unroll
        for (int b = 0; b < 3; ++b) acc[a][b] = (floatx4){0.f, 0.f, 0.f, 0.f};
    const short8* Bq = (const short8*)Bp;

    int p = m0 + lane;
    int n = p >> logHH, pp = p & ((1 << logHH) - 1);
    const float* xp = x + (((size_t)n * Cin) << logHH) + pp;

    for (int ks = 0; ks < KS; ++ks) {
        __syncthreads();
#pragma unroll
        for (int it = 0; it < 8; ++it) {
            int ciL = (tid >> 6) + it * 4;
            int ci = ks * 32 + ciL;
            float v = (ci < Cin) ? xp[(size_t)ci << logHH] : 0.f;
            As[lane * 40 + ciL] = f2bf(v);
        }
        __syncthreads();
        short8 a0 = *(const short8*)(&As[(wm * 32 + l15) * 40 + g * 8]);
        short8 a1 = *(const short8*)(&As[(wm * 32 + 16 + l15) * 40 + g * 8]);
        int bbase = (ks * 4 + g) * 96 + wn * 48 + l15;
#pragma unroll
        for (int nf = 0; nf < 3; ++nf) {
            short8 b = Bq[bbase + nf * 16];
            acc[0][nf] = __builtin_amdgcn_mfma_f32_16x16x32_bf16(a0, b, acc[0][nf], 0, 0, 0);
            acc[1][nf] = __builtin_amdgcn_mfma_f32_16x16x32_bf16(a1, b, acc[1][nf], 0, 0, 0);
        }
    }
    float bc[3];
#pragma unroll
    for (int nf = 0; nf < 3; ++nf) {
        int c = wn * 48 + nf * 16 + l15;
        bc[nf] = (c < 88) ? bias[c] : 0.f;
    }
#pragma unroll
    for (int mf = 0; mf < 2; ++mf)
#pragma unroll
        for (int r = 0; r < 4; ++r) {
            int pl = m0 + wm * 32 + mf * 16 + g * 4 + r;
#pragma unroll
            for (int nf = 0; nf < 3; ++nf) {
                int c = wn * 48 + nf * 16 + l15;
                out[(size_t)pl * 96 + c] = f2bf(acc[mf][nf][r] + bc[nf]);
            }
        }
}

// ---------------------------------------------------------------------------
// Fused BiFPN step work unit (64 pixels): fuse -> dw 3x3 -> pw MFMA + ReLU.
// mode 0: a + up2(b); 1: a + down2(b); 2: a + b + down2(c).
// ---------------------------------------------------------------------------
__device__ void sepconv_work(int mode, const ushort* __restrict__ a,
                             const ushort* __restrict__ bsrc, const ushort* __restrict__ csrc,
                             const float* __restrict__ fw, const float* __restrict__ dww,
                             const ushort* __restrict__ Bp, const float* __restrict__ pbias,
                             ushort* __restrict__ out, int logW, int blk,
                             ushort* Fs, ushort* Ds, ushort* Dwb) {
    int tid = threadIdx.x;
    int W = 1 << logW, HH = W * W, log2HH = 2 * logW;
    int Mlv = 4 * HH;
    int HB = W + 1;
    int RS = 64 + 2 * HB;
    int pl0 = blk * 64;
    float w0 = fmaxf(fw[0], 0.f), w1 = fmaxf(fw[1], 0.f);
    float w2 = (mode == 2) ? fmaxf(fw[2], 0.f) : 0.f;
    float inv = 1.f / (w0 + w1 + w2 + 1e-4f);
    float w0i = w0 * inv, w1i = w1 * inv, w2i = w2 * inv;

    if (tid < 13) *(uint4*)(&Fs[194 * 104 + tid * 8]) = (uint4){0u, 0u, 0u, 0u};
    for (int i = tid; i < 108; i += 256) {
        int cg = i / 9, tap = i - cg * 9;
        ushort tmp[8];
#pragma unroll
        for (int j = 0; j < 8; ++j) {
            int c = cg * 8 + j;
            tmp[j] = (c < 88) ? f2bf(dww[c * 9 + tap]) : (ushort)0;
        }
        *(uint4*)(&Dwb[i * 8]) = *(uint4*)tmp;
    }
    for (int i = tid; i < RS * 12; i += 256) {
        int row = i / 12, cg = i - row * 12;
        int pl = pl0 - HB + row;
        uint4 res = {0u, 0u, 0u, 0u};
        if (pl >= 0 && pl < Mlv) {
            int n = pl >> log2HH, pp = pl & (HH - 1);
            int y = pp >> logW, x = pp & (W - 1);
            uint4 av = *(const uint4*)(a + (size_t)pl * 96 + cg * 8);
            const ushort* au = (const ushort*)&av;
            float f[8];
            if (mode == 0) {
                int Wh = W >> 1;
                int bp = (n << (log2HH - 2)) + (y >> 1) * Wh + (x >> 1);
                uint4 bv = *(const uint4*)(bsrc + (size_t)bp * 96 + cg * 8);
                const ushort* bu = (const ushort*)&bv;
#pragma unroll
                for (int j = 0; j < 8; ++j)
                    f[j] = w0i * bf2f(au[j]) + w1i * bf2f(bu[j]);
            } else {
                int W2 = W << 1;
                const ushort* q = (mode == 1 ? bsrc : csrc) +
                    ((size_t)((n << (log2HH + 2)) + (2 * y) * W2 + 2 * x)) * 96 + cg * 8;
                uint4 q0 = *(const uint4*)(q);
                uint4 q1 = *(const uint4*)(q + 96);
                uint4 q2 = *(const uint4*)(q + (size_t)W2 * 96);
                uint4 q3 = *(const uint4*)(q + (size_t)W2 * 96 + 96);
                const ushort* u0 = (const ushort*)&q0; const ushort* u1 = (const ushort*)&q1;
                const ushort* u2 = (const ushort*)&q2; const ushort* u3 = (const ushort*)&q3;
                if (mode == 1) {
#pragma unroll
                    for (int j = 0; j < 8; ++j) {
                        float m = fmaxf(fmaxf(bf2f(u0[j]), bf2f(u1[j])),
                                        fmaxf(bf2f(u2[j]), bf2f(u3[j])));
                        f[j] = w0i * bf2f(au[j]) + w1i * m;
                    }
                } else {
                    uint4 b2v = *(const uint4*)(bsrc + (size_t)pl * 96 + cg * 8);
                    const ushort* b2u = (const ushort*)&b2v;
#pragma unroll
                    for (int j = 0; j < 8; ++j) {
                        float m = fmaxf(fmaxf(bf2f(u0[j]), bf2f(u1[j])),
                                        fmaxf(bf2f(u2[j]), bf2f(u3[j])));
                        f[j] = w0i * bf2f(au[j]) + w1i * bf2f(b2u[j]) + w2i * m;
                    }
                }
            }
            ushort tmp[8];
#pragma unroll
            for (int j = 0; j < 8; ++j) tmp[j] = f2bf(f[j]);
            res = *(uint4*)tmp;
        }
        *(uint4*)(&Fs[row * 104 + cg * 8]) = res;
    }
    __syncthreads();
    // depthwise 3x3 -> Ds
    for (int i = tid; i < 768; i += 256) {
        int row = i / 12, cg = i - row * 12;
        int pl = pl0 + row;
        int pp = pl & (HH - 1);
        int y = pp >> logW, x = pp & (W - 1);
        float acc8[8] = {0.f, 0.f, 0.f, 0.f, 0.f, 0.f, 0.f, 0.f};
        if (cg < 11) {
#pragma unroll
            for (int tap = 0; tap < 9; ++tap) {
                int dy = tap / 3 - 1, dx = tap % 3 - 1;
                int sy = y + dy, sx = x + dx;
                bool pred = ((unsigned)sy < (unsigned)W) && ((unsigned)sx < (unsigned)W);
                int rsel = pred ? (row + HB + dy * W + dx) : 194;
                short8 fv = *(const short8*)(&Fs[rsel * 104 + cg * 8]);
                short8 wv = *(const short8*)(&Dwb[(cg * 9 + tap) * 8]);
#pragma unroll
                for (int j = 0; j < 8; ++j)
                    acc8[j] = fmaf(bf2f((ushort)fv[j]), bf2f((ushort)wv[j]), acc8[j]);
            }
        }
        ushort tmp[8];
#pragma unroll
        for (int j = 0; j < 8; ++j) tmp[j] = f2bf(acc8[j]);
        *(uint4*)(&Ds[row * 104 + cg * 8]) = *(uint4*)tmp;
    }
    __syncthreads();
    // pointwise MFMA (Mt=64, N=96, K=96) + bias + ReLU
    int lane = tid & 63, l15 = lane & 15, g = (lane >> 4) & 3;
    int wave = tid >> 6, wm = wave & 1, wn = wave >> 1;
    floatx4 acc[2][3];
#pragma unroll
    for (int aa = 0; aa < 2; ++aa)
#pragma unroll
        for (int bb = 0; bb < 3; ++bb) acc[aa][bb] = (floatx4){0.f, 0.f, 0.f, 0.f};
    const short8* Bq = (const short8*)Bp;
#pragma unroll
    for (int ks = 0; ks < 3; ++ks) {
        int k = ks * 32 + g * 8;
        short8 a0 = *(const short8*)(&Ds[(wm * 32 + l15) * 104 + k]);
        short8 a1 = *(const short8*)(&Ds[(wm * 32 + 16 + l15) * 104 + k]);
        int bbase = (ks * 4 + g) * 96 + wn * 48 + l15;
#pragma unroll
        for (int nf = 0; nf < 3; ++nf) {
            short8 b = Bq[bbase + nf * 16];
            acc[0][nf] = __builtin_amdgcn_mfma_f32_16x16x32_bf16(a0, b, acc[0][nf], 0, 0, 0);
            acc[1][nf] = __builtin_amdgcn_mfma_f32_16x16x32_bf16(a1, b, acc[1][nf], 0, 0, 0);
        }
    }
    float bc[3];
#pragma unroll
    for (int nf = 0; nf < 3; ++nf) {
        int c = wn * 48 + nf * 16 + l15;
        bc[nf] = (c < 88) ? pbias[c] : 0.f;
    }
#pragma unroll
    for (int mf = 0; mf < 2; ++mf)
#pragma unroll
        for (int r = 0; r < 4; ++r) {
            int pl = pl0 + wm * 32 + mf * 16 + g * 4 + r;
#pragma unroll
            for (int nf = 0; nf < 3; ++nf) {
                int c = wn * 48 + nf * 16 + l15;
                out[(size_t)pl * 96 + c] = f2bf(fmaxf(acc[mf][nf][r] + bc[nf], 0.f));
            }
        }
}

// ---------------------------------------------------------------------------
// Persistent BiFPN mega-kernel: laterals + 3 stages x 8 fused sep-conv steps,
// separated by device-scope grid barriers. Grid = 256 blocks (co-resident:
// 55.6 KB LDS, 256 thr -> every CU holds its block; 25 single-use counters).
// ---------------------------------------------------------------------------
__global__ __launch_bounds__(256)
void bifpn_mega_k(const float* __restrict__ c3, const float* __restrict__ c4,
                  const float* __restrict__ c5, const float* __restrict__ c6,
                  const float* __restrict__ c7,
                  const float* __restrict__ lb3, const float* __restrict__ lb4,
                  const float* __restrict__ lb5, const float* __restrict__ lb6,
                  const float* __restrict__ lb7,
                  const ushort* __restrict__ BP_LAT,
                  const float* __restrict__ bif_dw, const float* __restrict__ bif_pb,
                  const float* __restrict__ bif_fw2, const float* __restrict__ bif_fw3,
                  const ushort* __restrict__ BP_PW,
                  ushort* __restrict__ CA, ushort* __restrict__ CB,
                  ushort* __restrict__ T4, ushort* __restrict__ T5, ushort* __restrict__ T6,
                  int* __restrict__ cnt) {
    __shared__ ushort Fs[195 * 104];
    __shared__ ushort Ds[64 * 104];
    __shared__ ushort Dwb[108 * 8];
    const int NB = gridDim.x;   // 256
    int bi = 0;

    // ---- laterals: 341 work units over 256 blocks ----
    {
        const float* xs[5] = {c3, c4, c5, c6, c7};
        const float* bs[5] = {lb3, lb4, lb5, lb6, lb7};
        const int CINL[5] = {40, 80, 112, 192, 320};
        const int KSL[5]  = {2, 3, 4, 6, 10};
        const int LATO[5] = {0, 6144, 15360, 27648, 46080};
        const int WOFF[6] = {0, 256, 320, 336, 340, 341};
        const int ROFF[5] = {0, 16384, 20480, 21504, 21760};
        for (int w = blockIdx.x; w < 341; w += NB) {
            int l = 0;
            while (w >= WOFF[l + 1]) ++l;
            int blk = w - WOFF[l];
            lateral_work(xs[l], BP_LAT + LATO[l], bs[l], CA + (size_t)ROFF[l] * 96,
                         CINL[l], KSL[l], 2 * (6 - l), blk, Fs /*reuse as As*/);
        }
    }
    gbar(&cnt[bi++], NB);

    // ---- 3 BiFPN stages ----
    ushort* cur = CA; ushort* nxt = CB;
    const int ROFF[5] = {0, 16384, 20480, 21504, 21760};
    for (int s = 0; s < 3; ++s) {
        const float* dws = bif_dw + (size_t)s * 8 * 792;
        const float* pbs = bif_pb + (size_t)s * 8 * 88;
        const float* f2  = bif_fw2 + (size_t)s * 10;
        const float* f3  = bif_fw3 + (size_t)s * 9;
        const ushort* PW = BP_PW + (size_t)s * 8 * BSLAB;
        int bx = blockIdx.x;

        // step 0: p6t (H=8, 4 blocks)
        if (bx < 4) sepconv_work(0, cur + (size_t)ROFF[3]*96, cur + (size_t)ROFF[4]*96, nullptr,
                                 f2 + 0, dws + 0*792, PW + 0*BSLAB, pbs + 0*88, T6, 3, bx, Fs, Ds, Dwb);
        gbar(&cnt[bi++], NB);
        // step 1: p5t (H=16, 16 blocks)
        if (bx < 16) sepconv_work(0, cur + (size_t)ROFF[2]*96, T6, nullptr,
                                  f2 + 2, dws + 1*792, PW + 1*BSLAB, pbs + 1*88, T5, 4, bx, Fs, Ds, Dwb);
        gbar(&cnt[bi++], NB);
        // step 2: p4t (H=32, 64 blocks)
        if (bx < 64) sepconv_work(0, cur + (size_t)ROFF[1]*96, T5, nullptr,
                                  f2 + 4, dws + 2*792, PW + 2*BSLAB, pbs + 2*88, T4, 5, bx, Fs, Ds, Dwb);
        gbar(&cnt[bi++], NB);
        // step 3: p3o (H=64, 256 blocks)
        sepconv_work(0, cur + (size_t)ROFF[0]*96, T4, nullptr,
                     f2 + 6, dws + 3*792, PW + 3*BSLAB, pbs + 3*88, nxt + (size_t)ROFF[0]*96, 6, bx, Fs, Ds, Dwb);
        gbar(&cnt[bi++], NB);
        // step 4: p4o (H=32)
        if (bx < 64) sepconv_work(2, cur + (size_t)ROFF[1]*96, T4, nxt + (size_t)ROFF[0]*96,
                                  f3 + 0, dws + 4*792, PW + 4*BSLAB, pbs + 4*88, nxt + (size_t)ROFF[1]*96, 5, bx, Fs, Ds, Dwb);
        gbar(&cnt[bi++], NB);
        // step 5: p5o (H=16)
        if (bx < 16) sepconv_work(2, cur + (size_t)ROFF[2]*96, T5, nxt + (size_t)ROFF[1]*96,
                                  f3 + 3, dws + 5*792, PW + 5*BSLAB, pbs + 5*88, nxt + (size_t)ROFF[2]*96, 4, bx, Fs, Ds, Dwb);
        gbar(&cnt[bi++], NB);
        // step 6: p6o (H=8)
        if (bx < 4) sepconv_work(2, cur + (size_t)ROFF[3]*96, T6, nxt + (size_t)ROFF[2]*96,
                                 f3 + 6, dws + 6*792, PW + 6*BSLAB, pbs + 6*88, nxt + (size_t)ROFF[3]*96, 3, bx, Fs, Ds, Dwb);
        gbar(&cnt[bi++], NB);
        // step 7: p7o (H=4, 1 block)
        if (bx < 1) sepconv_work(1, cur + (size_t)ROFF[4]*96, nxt + (size_t)ROFF[3]*96, nullptr,
                                 f2 + 8, dws + 7*792, PW + 7*BSLAB, pbs + 7*88, nxt + (size_t)ROFF[4]*96, 2, bx, Fs, Ds, Dwb);
        gbar(&cnt[bi++], NB);

        ushort* tp = cur; cur = nxt; nxt = tp;
    }
    // result in CB after odd number of swaps? 3 swaps: CA->CB->CA->CB: final cur=CB.
}

// ---------------------------------------------------------------------------
// Pipelined tower conv 3x3 (round-7 Mt=64 version): B slabs DMA'd to LDS one
// tap ahead (double buffer), A direct from global. Dual-head via blockIdx.y.
// ---------------------------------------------------------------------------
__global__ __launch_bounds__(256)
void tower_pipe_k(const ushort* __restrict__ inR, const ushort* __restrict__ inC,
                  const ushort* __restrict__ BpR, const ushort* __restrict__ BpC,
                  const float* __restrict__ bR, const float* __restrict__ bC,
                  ushort* __restrict__ outR, ushort* __restrict__ outC,
                  const ushort* __restrict__ zb) {
    __shared__ __align__(16) ushort Bs[2][BSLAB];
    int head = blockIdx.y;
    const ushort* in = head ? inC : inR;
    const ushort* Bg = head ? BpC : BpR;
    const float* bias = head ? bC : bR;
    ushort* out = head ? outC : outR;
    int tid = threadIdx.x;
    int m0 = blockIdx.x * 64;
    int lvl, base; lvl_of(m0, lvl, base);
    int logW = 6 - lvl, W = 1 << logW, HH = W * W;
    int pl0 = m0 - base;
    int lane = tid & 63, l15 = lane & 15, g = (lane >> 4) & 3;
    int wave = tid >> 6, wm = wave & 1, wn = wave >> 1;
    int ym[2], xm[2];
    const ushort* pbase[2];
#pragma unroll
    for (int mf = 0; mf < 2; ++mf) {
        int pl = pl0 + wm * 32 + mf * 16 + l15;
        int pp = pl & (HH - 1);
        ym[mf] = pp >> logW; xm[mf] = pp & (W - 1);
        pbase[mf] = in + (size_t)(base + pl) * 96 + g * 8;
    }
    const ushort* zbg = zb + g * 8;
    int fragoff = (g * 96 + wn * 48 + l15) * 8;

    auto stage = [&](int tap) {
        const ushort* src = Bg + tap * BSLAB;
        ushort* dst = (ushort*)Bs[tap & 1];
#pragma unroll
        for (int it = 0; it < 5; ++it) {
            int c = tid + it * 256;
            if (c < 1152) gld_lds16(src + (size_t)c * 8, dst + (size_t)c * 8);
        }
    };

    floatx4 acc[2][3];
#pragma unroll
    for (int aa = 0; aa < 2; ++aa)
#pragma unroll
        for (int bb = 0; bb < 3; ++bb) acc[aa][bb] = (floatx4){0.f, 0.f, 0.f, 0.f};

    stage(0);
    __syncthreads();
#pragma unroll
    for (int tap = 0; tap < 9; ++tap) {
        if (tap < 8) stage(tap + 1);
        const ushort* Bb = (const ushort*)Bs[tap & 1];
        const int dy = tap / 3 - 1, dx = tap % 3 - 1;
        int off96 = (dy * W + dx) * 96;
        const ushort* ap[2];
#pragma unroll
        for (int mf = 0; mf < 2; ++mf) {
            bool pred = ((unsigned)(ym[mf] + dy) < (unsigned)W) &&
                        ((unsigned)(xm[mf] + dx) < (unsigned)W);
            ap[mf] = pred ? (pbase[mf] + off96) : zbg;
        }
#pragma unroll
        for (int ks = 0; ks < 3; ++ks) {
            short8 a0 = *(const short8*)(ap[0] + ks * 32);
            short8 a1 = *(const short8*)(ap[1] + ks * 32);
            const ushort* bb = Bb + ks * 3072 + fragoff;
#pragma unroll
            for (int nf = 0; nf < 3; ++nf) {
                short8 b = *(const short8*)(bb + nf * 128);
                acc[0][nf] = __builtin_amdgcn_mfma_f32_16x16x32_bf16(a0, b, acc[0][nf], 0, 0, 0);
                acc[1][nf] = __builtin_amdgcn_mfma_f32_16x16x32_bf16(a1, b, acc[1][nf], 0, 0, 0);
            }
        }
        __syncthreads();
    }
    float bc[3];
#pragma unroll
    for (int nf = 0; nf < 3; ++nf) {
        int c = wn * 48 + nf * 16 + l15;
        bc[nf] = (c < 88) ? bias[c] : 0.f;
    }
#pragma unroll
    for (int mf = 0; mf < 2; ++mf)
#pragma unroll
        for (int r = 0; r < 4; ++r) {
            int pl = pl0 + wm * 32 + mf * 16 + g * 4 + r;
#pragma unroll
            for (int nf = 0; nf < 3; ++nf) {
                int c = wn * 48 + nf * 16 + l15;
                out[(size_t)(base + pl) * 96 + c] = f2bf(fmaxf(acc[mf][nf][r] + bc[nf], 0.f));
            }
        }
}

// ---------------------------------------------------------------------------
// Pipelined fused output heads (round-7 Mt=64 version): grid (341, 10).
// y=0 -> regression, y>=1 -> cls n-block y-1 (+sigmoid).
// ---------------------------------------------------------------------------
__global__ __launch_bounds__(256)
void heads_pipe_k(const ushort* __restrict__ xr, const ushort* __restrict__ xc,
                  const ushort* __restrict__ BpR, const ushort* __restrict__ BpC,
                  const float* __restrict__ bR, const float* __restrict__ bC,
                  float* __restrict__ outR, float* __restrict__ outC,
                  const ushort* __restrict__ zb) {
    __shared__ __align__(16) ushort Bs[2][BSLAB];
    int yb = blockIdx.y;
    bool isReg = (yb == 0);
    const ushort* in = isReg ? xr : xc;
    const ushort* Bg = isReg ? BpR : (BpC + (size_t)(yb - 1) * 9 * BSLAB);
    const float* bias = isReg ? bR : bC;
    float* outb = isReg ? outR : outC;
    const int C9 = isReg ? 36 : 810;
    const int OC = isReg ? 4 : 90;
    const int n0b = isReg ? 0 : (yb - 1) * 96;

    int tid = threadIdx.x;
    int m0 = blockIdx.x * 64;
    int lvl, base; lvl_of(m0, lvl, base);
    int logW = 6 - lvl, W = 1 << logW, HH = W * W, log2HH = 2 * logW;
    int pl0 = m0 - base;
    int lane = tid & 63, l15 = lane & 15, g = (lane >> 4) & 3;
    int wave = tid >> 6, wm = wave & 1, wn = wave >> 1;
    int ym[2], xm[2];
    const ushort* pbase[2];
#pragma unroll
    for (int mf = 0; mf < 2; ++mf) {
        int pl = pl0 + wm * 32 + mf * 16 + l15;
        int pp = pl & (HH - 1);
        ym[mf] = pp >> logW; xm[mf] = pp & (W - 1);
        pbase[mf] = in + (size_t)(base + pl) * 96 + g * 8;
    }
    const ushort* zbg = zb + g * 8;
    int fragoff = (g * 96 + wn * 48 + l15) * 8;

    auto stage = [&](int tap) {
        const ushort* src = Bg + tap * BSLAB;
        ushort* dst = (ushort*)Bs[tap & 1];
#pragma unroll
        for (int it = 0; it < 5; ++it) {
            int c = tid + it * 256;
            if (c < 1152) gld_lds16(src + (size_t)c * 8, dst + (size_t)c * 8);
        }
    };

    floatx4 acc[2][3];
#pragma unroll
    for (int aa = 0; aa < 2; ++aa)
#pragma unroll
        for (int bb = 0; bb < 3; ++bb) acc[aa][bb] = (floatx4){0.f, 0.f, 0.f, 0.f};

    stage(0);
    __syncthreads();
#pragma unroll
    for (int tap = 0; tap < 9; ++tap) {
        if (tap < 8) stage(tap + 1);
        const ushort* Bb = (const ushort*)Bs[tap & 1];
        const int dy = tap / 3 - 1, dx = tap % 3 - 1;
        int off96 = (dy * W + dx) * 96;
        const ushort* ap[2];
#pragma unroll
        for (int mf = 0; mf < 2; ++mf) {
            bool pred = ((unsigned)(ym[mf] + dy) < (unsigned)W) &&
                        ((unsigned)(xm[mf] + dx) < (unsigned)W);
            ap[mf] = pred ? (pbase[mf] + off96) : zbg;
        }
#pragma unroll
        for (int ks = 0; ks < 3; ++ks) {
            short8 a0 = *(const short8*)(ap[0] + ks * 32);
            short8 a1 = *(const short8*)(ap[1] + ks * 32);
            const ushort* bb = Bb + ks * 3072 + fragoff;
#pragma unroll
            for (int nf = 0; nf < 3; ++nf) {
                short8 b = *(const short8*)(bb + nf * 128);
                acc[0][nf] = __builtin_amdgcn_mfma_f32_16x16x32_bf16(a0, b, acc[0][nf], 0, 0, 0);
                acc[1][nf] = __builtin_amdgcn_mfma_f32_16x16x32_bf16(a1, b, acc[1][nf], 0, 0, 0);
            }
        }
        __syncthreads();
    }
#pragma unroll
    for (int nf = 0; nf < 3; ++nf) {
        int c = n0b + wn * 48 + nf * 16 + l15;
        if (c >= C9) continue;
        float bcv = bias[c];
        int a = c / OC, kk = c - a * OC;
#pragma unroll
        for (int mf = 0; mf < 2; ++mf)
#pragma unroll
            for (int r = 0; r < 4; ++r) {
                int pl = pl0 + wm * 32 + mf * 16 + g * 4 + r;
                int n = pl >> log2HH, pp = pl & (HH - 1);
                float v = acc[mf][nf][r] + bcv;
                if (!isReg) v = 1.f / (1.f + expf(-v));
                outb[((size_t)n * 49104 + LOFFc[lvl] + (size_t)pp * 9 + a) * OC + kk] = v;
            }
    }
}

// ---------------------------------------------------------------------------
// anchors + zero-buffer init (zb: 96 ushorts = 48 uints)
__global__ void anchors_k(float* __restrict__ out, ushort* __restrict__ zb) {
    int idx = blockIdx.x * blockDim.x + threadIdx.x;
    if (idx < 48) ((unsigned int*)zb)[idx] = 0u;
    if (idx >= 49104) return;
    const int offs[6] = {0, 36864, 46080, 48384, 48960, 49104};
    int l = 0;
    while (idx >= offs[l + 1]) ++l;
    int j = idx - offs[l];
    int a = j % 9;
    int p = j / 9;
    int fs = 64 >> l;
    int stride = 8 << l;
    float size = (float)(32 << l);
    int ix = p % fs, iy = p / fs;
    float cx = (ix + 0.5f) * (float)stride;
    float cy = (iy + 0.5f) * (float)stride;
    const float scl[3] = {1.0f, 1.2599210498948732f, 1.5874010519681994f};
    const float sqr[3] = {0.7071067811865476f, 1.0f, 1.4142135623730951f};
    int r = a / 3, s = a % 3;
    float w = size * scl[s] / sqr[r];
    float h = size * scl[s] * sqr[r];
    float* o = out + (size_t)idx * 4;
    o[0] = cx - 0.5f * w;
    o[1] = cy - 0.5f * h;
    o[2] = cx + 0.5f * w;
    o[3] = cy + 0.5f * h;
}

// ---------------------------------------------------------------------------

extern "C" void kernel_launch(void* const* d_in, const int* in_sizes, int n_in,
                              void* d_out, int out_size, void* d_ws, size_t ws_size,
                              hipStream_t stream) {
    const float* c_in[5]  = {(const float*)d_in[0],  (const float*)d_in[3],
                             (const float*)d_in[6],  (const float*)d_in[9],
                             (const float*)d_in[12]};
    const float* lat_w[5] = {(const float*)d_in[1],  (const float*)d_in[4],
                             (const float*)d_in[7],  (const float*)d_in[10],
                             (const float*)d_in[13]};
    const float* lat_b[5] = {(const float*)d_in[2],  (const float*)d_in[5],
                             (const float*)d_in[8],  (const float*)d_in[11],
                             (const float*)d_in[14]};
    const float* bif_dw  = (const float*)d_in[15];
    const float* bif_pw  = (const float*)d_in[16];
    const float* bif_pb  = (const float*)d_in[17];
    const float* bif_fw2 = (const float*)d_in[18];
    const float* bif_fw3 = (const float*)d_in[19];
    const float* reg_tw  = (const float*)d_in[20];
    const float* reg_tb  = (const float*)d_in[21];
    const float* reg_ow  = (const float*)d_in[22];
    const float* reg_ob  = (const float*)d_in[23];
    const float* cls_tw  = (const float*)d_in[24];
    const float* cls_tb  = (const float*)d_in[25];
    const float* cls_ow  = (const float*)d_in[26];
    const float* cls_ob  = (const float*)d_in[27];

    const size_t CONC = (size_t)CONC_ROWS * 96;

    int* CNT = (int*)d_ws;                 // 32 counters (128 B), memset to 0
    ushort* ws = (ushort*)d_ws + 64;
    size_t off = 0;
    ushort* CA = ws + off; off += CONC;
    ushort* CB = ws + off; off += CONC;
    ushort* T4 = ws + off; off += (size_t)4096 * 96;
    ushort* T5 = ws + off; off += (size_t)1024 * 96;
    ushort* T6 = ws + off; off += (size_t)256 * 96;
    ushort* HXR0 = ws + off; off += CONC;
    ushort* HXR1 = ws + off; off += CONC;
    ushort* HXC0 = ws + off; off += CONC;
    ushort* HXC1 = ws + off; off += CONC;
    ushort* BP_PW  = ws + off; off += (size_t)24 * BSLAB;
    ushort* BP_TW  = ws + off; off += (size_t)8 * 82944;
    ushort* BP_RO  = ws + off; off += (size_t)82944;
    ushort* BP_CO  = ws + off; off += (size_t)746496;
    ushort* BP_LAT = ws + off; off += (size_t)76800;
    ushort* ZB     = ws + off; off += 96;
    (void)ws_size; (void)n_in; (void)in_sizes; (void)out_size;

    // ---- barrier counters -> 0 ----
    hipMemsetAsync(d_ws, 0, 128, stream);

    // ---- merged packing (1 dispatch) ----
    pack_all_k<<<cdiv(1790976, TPB), TPB, 0, stream>>>(
        bif_pw, reg_tw, cls_tw, reg_ow, cls_ow,
        lat_w[0], lat_w[1], lat_w[2], lat_w[3], lat_w[4],
        BP_PW, BP_TW, BP_RO, BP_CO, BP_LAT);

    // ---- anchors + zero buffer ----
    float* cls_base = (float*)d_out;
    float* reg_base = cls_base + (size_t)4 * 49104 * 90;
    float* anc_base = reg_base + (size_t)4 * 49104 * 4;
    anchors_k<<<cdiv(49104, TPB), TPB, 0, stream>>>(anc_base, ZB);

    // ---- laterals + full BiFPN in ONE persistent kernel ----
    bifpn_mega_k<<<256, 256, 0, stream>>>(
        c_in[0], c_in[1], c_in[2], c_in[3], c_in[4],
        lat_b[0], lat_b[1], lat_b[2], lat_b[3], lat_b[4],
        BP_LAT, bif_dw, bif_pb, bif_fw2, bif_fw3, BP_PW,
        CA, CB, T4, T5, T6, CNT);
    // after 3 stages (odd swaps), final pyramid is in CB
    ushort* cur = CB;

    // ---- heads: pipelined towers + fused output convs (round-7 config) ----
    const int GB = CONC_ROWS / 64;  // 341
    ushort* hxr[2] = {HXR0, HXR1};
    ushort* hxc[2] = {HXC0, HXC1};
    const ushort* xr = cur;
    const ushort* xc = cur;
    for (int i = 0; i < 4; ++i) {
        tower_pipe_k<<<dim3(GB, 2), 256, 0, stream>>>(
            xr, xc, BP_TW + (size_t)i * 82944, BP_TW + (size_t)(4 + i) * 82944,
            reg_tb + i * 88, cls_tb + i * 88, hxr[i & 1], hxc[i & 1], ZB);
        xr = hxr[i & 1]; xc = hxc[i & 1];
    }
    heads_pipe_k<<<dim3(GB, 10), 256, 0, stream>>>(
        xr, xc, BP_RO, BP_CO, reg_ob, cls_ob, reg_base, cls_base, ZB);
}

// Round 11
// 616.908 us; speedup vs baseline: 2.7369x; 2.7369x over previous
//
#include <hip/hip_runtime.h>
#include <math.h>

#define TPB 256
static inline int cdiv(int a, int b) { return (a + b - 1) / b; }

typedef __attribute__((ext_vector_type(8))) short short8;
typedef __attribute__((ext_vector_type(4))) float floatx4;

__device__ __forceinline__ float bf2f(ushort u) {
    union { unsigned int u; float f; } v; v.u = ((unsigned int)u) << 16; return v.f;
}
__device__ __forceinline__ ushort f2bf(float f) {
    union { float f; unsigned int u; } v; v.f = f;
    unsigned int r = (v.u + 0x7FFFu + ((v.u >> 16) & 1u)) >> 16;
    return (ushort)r;
}

// Concatenated pyramid layout: rows [0,16384) l0(H=64), [16384,20480) l1(H=32),
// [20480,21504) l2(H=16), [21504,21760) l3(H=8), [21760,21824) l4(H=4).
#define CONC_ROWS 21824
__device__ __forceinline__ void lvl_of(int row, int& lvl, int& base) {
    lvl = 0; base = 0;
    if (row >= 16384) { lvl = 1; base = 16384; }
    if (row >= 20480) { lvl = 2; base = 20480; }
    if (row >= 21504) { lvl = 3; base = 21504; }
    if (row >= 21760) { lvl = 4; base = 21760; }
}
__constant__ int LOFFc[5] = {0, 36864, 46080, 48384, 48960};

// B slab per tap: [3ks][4g][96n][8j] = 9216 ushorts = 18432 B = 1152 x 16B
#define BSLAB 9216

// async global->LDS 16B DMA
__device__ __forceinline__ void gld_lds16(const ushort* g, ushort* l) {
    __builtin_amdgcn_global_load_lds(
        (const __attribute__((address_space(1))) unsigned int*)g,
        (__attribute__((address_space(3))) unsigned int*)l, 16, 0, 0);
}

// ---------------------------------------------------------------------------
// Merged weight packing: one kernel, range-dispatched.
// pw:  [0, 221184)           24 x [3ks][4g][96n][8j]
// tw8: [221184, 884736)      8 tower convs
// ro:  [884736, 967680)      reg out (Ntot=96, CO=36)
// co:  [967680, 1714176)     cls out [9nb][9tap][3ks][4g][96n][8j]
// lat: [1714176, 1790976)    5 laterals
// ---------------------------------------------------------------------------
__global__ void pack_all_k(const float* __restrict__ pw, const float* __restrict__ rw,
                           const float* __restrict__ cw, const float* __restrict__ row_,
                           const float* __restrict__ cow,
                           const float* __restrict__ w3, const float* __restrict__ w4,
                           const float* __restrict__ w5, const float* __restrict__ w6,
                           const float* __restrict__ w7,
                           ushort* __restrict__ BP_PW, ushort* __restrict__ BP_TW,
                           ushort* __restrict__ BP_RO, ushort* __restrict__ BP_CO,
                           ushort* __restrict__ BP_LAT) {
    int gid = blockIdx.x * blockDim.x + threadIdx.x;
    if (gid < 221184) {
        int idx = gid;
        int cid = idx / BSLAB; int r = idx - cid * BSLAB;
        int j = r & 7; int t = r >> 3;
        int n = t % 96; t /= 96;
        int g = t & 3; int ks = t >> 2;
        int ci = ks * 32 + g * 8 + j;
        float v = (ci < 88 && n < 88) ? pw[(size_t)cid * 7744 + n * 88 + ci] : 0.f;
        BP_PW[idx] = f2bf(v);
    } else if (gid < 884736) {
        int idx = gid - 221184;
        int i = idx / 82944; int r = idx - i * 82944;
        const float* w = (i < 4) ? rw + (size_t)i * 69696 : cw + (size_t)(i - 4) * 69696;
        int j = r & 7; int t = r >> 3;
        int n = t % 96; t /= 96;
        int g = t & 3; t >>= 2;
        int ks = t % 3; int tap = t / 3;
        int ci = ks * 32 + g * 8 + j;
        float v = (ci < 88 && n < 88) ? w[((size_t)n * 88 + ci) * 9 + tap] : 0.f;
        BP_TW[idx] = f2bf(v);
    } else if (gid < 967680) {
        int idx = gid - 884736;
        int j = idx & 7; int t = idx >> 3;
        int n = t % 96; t /= 96;
        int g = t & 3; t >>= 2;
        int ks = t % 3; int tap = t / 3;
        int ci = ks * 32 + g * 8 + j;
        float v = (ci < 88 && n < 36) ? row_[((size_t)n * 88 + ci) * 9 + tap] : 0.f;
        BP_RO[idx] = f2bf(v);
    } else if (gid < 1714176) {
        int idx = gid - 967680;
        int j = idx & 7; int t = idx >> 3;
        int n = t % 96; t /= 96;
        int g = t & 3; t >>= 2;
        int ks = t % 3; t /= 3;
        int tap = t % 9; int nb = t / 9;
        int ci = ks * 32 + g * 8 + j;
        int co = nb * 96 + n;
        float v = (ci < 88 && co < 810) ? cow[((size_t)co * 88 + ci) * 9 + tap] : 0.f;
        BP_CO[idx] = f2bf(v);
    } else if (gid < 1790976) {
        int idx = gid - 1714176;
        int l, off;
        if (idx < 6144)       { l = 0; off = 0; }
        else if (idx < 15360) { l = 1; off = 6144; }
        else if (idx < 27648) { l = 2; off = 15360; }
        else if (idx < 46080) { l = 3; off = 27648; }
        else                  { l = 4; off = 46080; }
        const float* w = l == 0 ? w3 : l == 1 ? w4 : l == 2 ? w5 : l == 3 ? w6 : w7;
        const int cins[5] = {40, 80, 112, 192, 320};
        int Cin = cins[l];
        int r = idx - off;
        int j = r & 7; int t = r >> 3;
        int n = t % 96; t /= 96;
        int g = t & 3; int ks = t >> 2;
        int ci = ks * 32 + g * 8 + j;
        float v = (ci < Cin && n < 88) ? w[(size_t)n * Cin + ci] : 0.f;
        BP_LAT[idx] = f2bf(v);
    }
}

// ---------------------------------------------------------------------------
// All 5 lateral convs in one dispatch (341 blocks, level decode).
// NCHW fp32 -> NHWC96 bf16, no act.
// ---------------------------------------------------------------------------
__global__ __launch_bounds__(256)
void lateral_all_k(const float* __restrict__ c3, const float* __restrict__ c4,
                   const float* __restrict__ c5, const float* __restrict__ c6,
                   const float* __restrict__ c7,
                   const float* __restrict__ lb3, const float* __restrict__ lb4,
                   const float* __restrict__ lb5, const float* __restrict__ lb6,
                   const float* __restrict__ lb7,
                   const ushort* __restrict__ BP_LAT, ushort* __restrict__ CA) {
    __shared__ ushort As[64 * 40];
    const float* xs[5] = {c3, c4, c5, c6, c7};
    const float* bs[5] = {lb3, lb4, lb5, lb6, lb7};
    const int CINL[5] = {40, 80, 112, 192, 320};
    const int KSL[5]  = {2, 3, 4, 6, 10};
    const int LATO[5] = {0, 6144, 15360, 27648, 46080};
    const int WOFF[6] = {0, 256, 320, 336, 340, 341};
    const int ROFF[5] = {0, 16384, 20480, 21504, 21760};
    int w = blockIdx.x;
    int l = 0;
    while (w >= WOFF[l + 1]) ++l;
    int m0 = (w - WOFF[l]) * 64;
    int Cin = CINL[l], KS = KSL[l], logHH = 2 * (6 - l);
    const float* x = xs[l];
    const float* bias = bs[l];
    const ushort* Bp = BP_LAT + LATO[l];
    ushort* out = CA + (size_t)ROFF[l] * 96;

    int tid = threadIdx.x;
    int lane = tid & 63, l15 = lane & 15, g = (lane >> 4) & 3;
    int wave = tid >> 6, wm = wave & 1, wn = wave >> 1;
    floatx4 acc[2][3];
#pragma unroll
    for (int a = 0; a < 2; ++a)
#pragma unroll
        for (int b = 0; b < 3; ++b) acc[a][b] = (floatx4){0.f, 0.f, 0.f, 0.f};
    const short8* Bq = (const short8*)Bp;

    int p = m0 + lane;
    int n = p >> logHH, pp = p & ((1 << logHH) - 1);
    const float* xp = x + (((size_t)n * Cin) << logHH) + pp;

    for (int ks = 0; ks < KS; ++ks) {
        __syncthreads();
#pragma unroll
        for (int it = 0; it < 8; ++it) {
            int ciL = (tid >> 6) + it * 4;
            int ci = ks * 32 + ciL;
            float v = (ci < Cin) ? xp[(size_t)ci << logHH] : 0.f;
            As[lane * 40 + ciL] = f2bf(v);
        }
        __syncthreads();
        short8 a0 = *(const short8*)(&As[(wm * 32 + l15) * 40 + g * 8]);
        short8 a1 = *(const short8*)(&As[(wm * 32 + 16 + l15) * 40 + g * 8]);
        int bbase = (ks * 4 + g) * 96 + wn * 48 + l15;
#pragma unroll
        for (int nf = 0; nf < 3; ++nf) {
            short8 b = Bq[bbase + nf * 16];
            acc[0][nf] = __builtin_amdgcn_mfma_f32_16x16x32_bf16(a0, b, acc[0][nf], 0, 0, 0);
            acc[1][nf] = __builtin_amdgcn_mfma_f32_16x16x32_bf16(a1, b, acc[1][nf], 0, 0, 0);
        }
    }
    float bc[3];
#pragma unroll
    for (int nf = 0; nf < 3; ++nf) {
        int c = wn * 48 + nf * 16 + l15;
        bc[nf] = (c < 88) ? bias[c] : 0.f;
    }
#pragma unroll
    for (int mf = 0; mf < 2; ++mf)
#pragma unroll
        for (int r = 0; r < 4; ++r) {
            int pl = m0 + wm * 32 + mf * 16 + g * 4 + r;
#pragma unroll
            for (int nf = 0; nf < 3; ++nf) {
                int c = wn * 48 + nf * 16 + l15;
                out[(size_t)pl * 96 + c] = f2bf(acc[mf][nf][r] + bc[nf]);
            }
        }
}

// ---------------------------------------------------------------------------
// Fully fused BiFPN step: fuse-op -> depthwise 3x3 -> pointwise MFMA + ReLU.
// MODE 0: 2-in (a + up2(b)); 1: 2-in (a + down2(b)); 2: 3-in (a + b + down2(c)).
// ---------------------------------------------------------------------------
template <int MODE>
__global__ __launch_bounds__(256, 2)
void sepconv_k(const ushort* __restrict__ a, const ushort* __restrict__ bsrc,
               const ushort* __restrict__ csrc, const float* __restrict__ fw,
               const float* __restrict__ dww, const ushort* __restrict__ Bp,
               const float* __restrict__ pbias, ushort* __restrict__ out,
               int logW) {
    __shared__ ushort Fs[195 * 104];   // fused input + halo; row 194 = zeros
    __shared__ ushort Ds[64 * 104];    // depthwise output (pw A-tile)
    __shared__ ushort Dwb[108 * 8];    // dw weights bf16 [cg][tap][8]
    int tid = threadIdx.x;
    int W = 1 << logW, HH = W * W, log2HH = 2 * logW;
    int Mlv = 4 * HH;
    int HB = W + 1;
    int RS = 64 + 2 * HB;
    int pl0 = blockIdx.x * 64;
    float w0 = fmaxf(fw[0], 0.f), w1 = fmaxf(fw[1], 0.f);
    float w2 = (MODE == 2) ? fmaxf(fw[2], 0.f) : 0.f;
    float inv = 1.f / (w0 + w1 + w2 + 1e-4f);
    float w0i = w0 * inv, w1i = w1 * inv, w2i = w2 * inv;

    if (tid < 13) *(uint4*)(&Fs[194 * 104 + tid * 8]) = (uint4){0u, 0u, 0u, 0u};
    for (int i = tid; i < 108; i += 256) {
        int cg = i / 9, tap = i - cg * 9;
        ushort tmp[8];
#pragma unroll
        for (int j = 0; j < 8; ++j) {
            int c = cg * 8 + j;
            tmp[j] = (c < 88) ? f2bf(dww[c * 9 + tap]) : (ushort)0;
        }
        *(uint4*)(&Dwb[i * 8]) = *(uint4*)tmp;
    }
    for (int i = tid; i < RS * 12; i += 256) {
        int row = i / 12, cg = i - row * 12;
        int pl = pl0 - HB + row;
        uint4 res = {0u, 0u, 0u, 0u};
        if (pl >= 0 && pl < Mlv) {
            int n = pl >> log2HH, pp = pl & (HH - 1);
            int y = pp >> logW, x = pp & (W - 1);
            uint4 av = *(const uint4*)(a + (size_t)pl * 96 + cg * 8);
            const ushort* au = (const ushort*)&av;
            float f[8];
            if (MODE == 0) {
                int Wh = W >> 1;
                int bp = (n << (log2HH - 2)) + (y >> 1) * Wh + (x >> 1);
                uint4 bv = *(const uint4*)(bsrc + (size_t)bp * 96 + cg * 8);
                const ushort* bu = (const ushort*)&bv;
#pragma unroll
                for (int j = 0; j < 8; ++j)
                    f[j] = w0i * bf2f(au[j]) + w1i * bf2f(bu[j]);
            } else {
                int W2 = W << 1;
                const ushort* q = (MODE == 1 ? bsrc : csrc) +
                    ((size_t)((n << (log2HH + 2)) + (2 * y) * W2 + 2 * x)) * 96 + cg * 8;
                uint4 q0 = *(const uint4*)(q);
                uint4 q1 = *(const uint4*)(q + 96);
                uint4 q2 = *(const uint4*)(q + (size_t)W2 * 96);
                uint4 q3 = *(const uint4*)(q + (size_t)W2 * 96 + 96);
                const ushort* u0 = (const ushort*)&q0; const ushort* u1 = (const ushort*)&q1;
                const ushort* u2 = (const ushort*)&q2; const ushort* u3 = (const ushort*)&q3;
                if (MODE == 1) {
#pragma unroll
                    for (int j = 0; j < 8; ++j) {
                        float m = fmaxf(fmaxf(bf2f(u0[j]), bf2f(u1[j])),
                                        fmaxf(bf2f(u2[j]), bf2f(u3[j])));
                        f[j] = w0i * bf2f(au[j]) + w1i * m;
                    }
                } else {
                    uint4 b2v = *(const uint4*)(bsrc + (size_t)pl * 96 + cg * 8);
                    const ushort* b2u = (const ushort*)&b2v;
#pragma unroll
                    for (int j = 0; j < 8; ++j) {
                        float m = fmaxf(fmaxf(bf2f(u0[j]), bf2f(u1[j])),
                                        fmaxf(bf2f(u2[j]), bf2f(u3[j])));
                        f[j] = w0i * bf2f(au[j]) + w1i * bf2f(b2u[j]) + w2i * m;
                    }
                }
            }
            ushort tmp[8];
#pragma unroll
            for (int j = 0; j < 8; ++j) tmp[j] = f2bf(f[j]);
            res = *(uint4*)tmp;
        }
        *(uint4*)(&Fs[row * 104 + cg * 8]) = res;
    }
    __syncthreads();
    // depthwise 3x3 -> Ds
    for (int i = tid; i < 768; i += 256) {
        int row = i / 12, cg = i - row * 12;
        int pl = pl0 + row;
        int pp = pl & (HH - 1);
        int y = pp >> logW, x = pp & (W - 1);
        float acc8[8] = {0.f, 0.f, 0.f, 0.f, 0.f, 0.f, 0.f, 0.f};
        if (cg < 11) {
#pragma unroll
            for (int tap = 0; tap < 9; ++tap) {
                int dy = tap / 3 - 1, dx = tap % 3 - 1;
                int sy = y + dy, sx = x + dx;
                bool pred = ((unsigned)sy < (unsigned)W) && ((unsigned)sx < (unsigned)W);
                int rsel = pred ? (row + HB + dy * W + dx) : 194;
                short8 fv = *(const short8*)(&Fs[rsel * 104 + cg * 8]);
                short8 wv = *(const short8*)(&Dwb[(cg * 9 + tap) * 8]);
#pragma unroll
                for (int j = 0; j < 8; ++j)
                    acc8[j] = fmaf(bf2f((ushort)fv[j]), bf2f((ushort)wv[j]), acc8[j]);
            }
        }
        ushort tmp[8];
#pragma unroll
        for (int j = 0; j < 8; ++j) tmp[j] = f2bf(acc8[j]);
        *(uint4*)(&Ds[row * 104 + cg * 8]) = *(uint4*)tmp;
    }
    __syncthreads();
    // pointwise MFMA (Mt=64, N=96, K=96) + bias + ReLU
    int lane = tid & 63, l15 = lane & 15, g = (lane >> 4) & 3;
    int wave = tid >> 6, wm = wave & 1, wn = wave >> 1;
    floatx4 acc[2][3];
#pragma unroll
    for (int aa = 0; aa < 2; ++aa)
#pragma unroll
        for (int bb = 0; bb < 3; ++bb) acc[aa][bb] = (floatx4){0.f, 0.f, 0.f, 0.f};
    const short8* Bq = (const short8*)Bp;
#pragma unroll
    for (int ks = 0; ks < 3; ++ks) {
        int k = ks * 32 + g * 8;
        short8 a0 = *(const short8*)(&Ds[(wm * 32 + l15) * 104 + k]);
        short8 a1 = *(const short8*)(&Ds[(wm * 32 + 16 + l15) * 104 + k]);
        int bbase = (ks * 4 + g) * 96 + wn * 48 + l15;
#pragma unroll
        for (int nf = 0; nf < 3; ++nf) {
            short8 b = Bq[bbase + nf * 16];
            acc[0][nf] = __builtin_amdgcn_mfma_f32_16x16x32_bf16(a0, b, acc[0][nf], 0, 0, 0);
            acc[1][nf] = __builtin_amdgcn_mfma_f32_16x16x32_bf16(a1, b, acc[1][nf], 0, 0, 0);
        }
    }
    float bc[3];
#pragma unroll
    for (int nf = 0; nf < 3; ++nf) {
        int c = wn * 48 + nf * 16 + l15;
        bc[nf] = (c < 88) ? pbias[c] : 0.f;
    }
#pragma unroll
    for (int mf = 0; mf < 2; ++mf)
#pragma unroll
        for (int r = 0; r < 4; ++r) {
            int pl = pl0 + wm * 32 + mf * 16 + g * 4 + r;
#pragma unroll
            for (int nf = 0; nf < 3; ++nf) {
                int c = wn * 48 + nf * 16 + l15;
                out[(size_t)pl * 96 + c] = f2bf(fmaxf(acc[mf][nf][r] + bc[nf], 0.f));
            }
        }
}

// ---------------------------------------------------------------------------
// Pipelined tower conv 3x3 (round-7 Mt=64): B slabs DMA'd to LDS one tap ahead
// (double buffer), A direct from global. Dual-head via blockIdx.y.
// ---------------------------------------------------------------------------
__global__ __launch_bounds__(256)
void tower_pipe_k(const ushort* __restrict__ inR, const ushort* __restrict__ inC,
                  const ushort* __restrict__ BpR, const ushort* __restrict__ BpC,
                  const float* __restrict__ bR, const float* __restrict__ bC,
                  ushort* __restrict__ outR, ushort* __restrict__ outC,
                  const ushort* __restrict__ zb) {
    __shared__ __align__(16) ushort Bs[2][BSLAB];
    int head = blockIdx.y;
    const ushort* in = head ? inC : inR;
    const ushort* Bg = head ? BpC : BpR;
    const float* bias = head ? bC : bR;
    ushort* out = head ? outC : outR;
    int tid = threadIdx.x;
    int m0 = blockIdx.x * 64;
    int lvl, base; lvl_of(m0, lvl, base);
    int logW = 6 - lvl, W = 1 << logW, HH = W * W;
    int pl0 = m0 - base;
    int lane = tid & 63, l15 = lane & 15, g = (lane >> 4) & 3;
    int wave = tid >> 6, wm = wave & 1, wn = wave >> 1;
    int ym[2], xm[2];
    const ushort* pbase[2];
#pragma unroll
    for (int mf = 0; mf < 2; ++mf) {
        int pl = pl0 + wm * 32 + mf * 16 + l15;
        int pp = pl & (HH - 1);
        ym[mf] = pp >> logW; xm[mf] = pp & (W - 1);
        pbase[mf] = in + (size_t)(base + pl) * 96 + g * 8;
    }
    const ushort* zbg = zb + g * 8;
    int fragoff = (g * 96 + wn * 48 + l15) * 8;

    auto stage = [&](int tap) {
        const ushort* src = Bg + tap * BSLAB;
        ushort* dst = (ushort*)Bs[tap & 1];
#pragma unroll
        for (int it = 0; it < 5; ++it) {
            int c = tid + it * 256;
            if (c < 1152) gld_lds16(src + (size_t)c * 8, dst + (size_t)c * 8);
        }
    };

    floatx4 acc[2][3];
#pragma unroll
    for (int aa = 0; aa < 2; ++aa)
#pragma unroll
        for (int bb = 0; bb < 3; ++bb) acc[aa][bb] = (floatx4){0.f, 0.f, 0.f, 0.f};

    stage(0);
    __syncthreads();
#pragma unroll
    for (int tap = 0; tap < 9; ++tap) {
        if (tap < 8) stage(tap + 1);
        const ushort* Bb = (const ushort*)Bs[tap & 1];
        const int dy = tap / 3 - 1, dx = tap % 3 - 1;
        int off96 = (dy * W + dx) * 96;
        const ushort* ap[2];
#pragma unroll
        for (int mf = 0; mf < 2; ++mf) {
            bool pred = ((unsigned)(ym[mf] + dy) < (unsigned)W) &&
                        ((unsigned)(xm[mf] + dx) < (unsigned)W);
            ap[mf] = pred ? (pbase[mf] + off96) : zbg;
        }
#pragma unroll
        for (int ks = 0; ks < 3; ++ks) {
            short8 a0 = *(const short8*)(ap[0] + ks * 32);
            short8 a1 = *(const short8*)(ap[1] + ks * 32);
            const ushort* bb = Bb + ks * 3072 + fragoff;
#pragma unroll
            for (int nf = 0; nf < 3; ++nf) {
                short8 b = *(const short8*)(bb + nf * 128);
                acc[0][nf] = __builtin_amdgcn_mfma_f32_16x16x32_bf16(a0, b, acc[0][nf], 0, 0, 0);
                acc[1][nf] = __builtin_amdgcn_mfma_f32_16x16x32_bf16(a1, b, acc[1][nf], 0, 0, 0);
            }
        }
        __syncthreads();
    }
    float bc[3];
#pragma unroll
    for (int nf = 0; nf < 3; ++nf) {
        int c = wn * 48 + nf * 16 + l15;
        bc[nf] = (c < 88) ? bias[c] : 0.f;
    }
#pragma unroll
    for (int mf = 0; mf < 2; ++mf)
#pragma unroll
        for (int r = 0; r < 4; ++r) {
            int pl = pl0 + wm * 32 + mf * 16 + g * 4 + r;
#pragma unroll
            for (int nf = 0; nf < 3; ++nf) {
                int c = wn * 48 + nf * 16 + l15;
                out[(size_t)(base + pl) * 96 + c] = f2bf(fmaxf(acc[mf][nf][r] + bc[nf], 0.f));
            }
        }
}

// ---------------------------------------------------------------------------
// Pipelined fused output heads with XCD-locality swizzle. Grid = 3440 x 1.
// Decode: r=id&7, t=id>>3, yb=t%10, x=(t/10)*8+r; all 10 yb of one m-tile
// share id%8 -> same XCD -> A rows fetched once per XCD instead of ~8x.
// y=0 -> regression, y>=1 -> cls n-block y-1 (+sigmoid).
// ---------------------------------------------------------------------------
__global__ __launch_bounds__(256)
void heads_pipe_k(const ushort* __restrict__ xr, const ushort* __restrict__ xc,
                  const ushort* __restrict__ BpR, const ushort* __restrict__ BpC,
                  const float* __restrict__ bR, const float* __restrict__ bC,
                  float* __restrict__ outR, float* __restrict__ outC,
                  const ushort* __restrict__ zb) {
    __shared__ __align__(16) ushort Bs[2][BSLAB];
    int id = blockIdx.x;
    int rr = id & 7, t = id >> 3;
    int yb = t % 10;
    int mx = (t / 10) * 8 + rr;
    if (mx >= 341) return;
    bool isReg = (yb == 0);
    const ushort* in = isReg ? xr : xc;
    const ushort* Bg = isReg ? BpR : (BpC + (size_t)(yb - 1) * 9 * BSLAB);
    const float* bias = isReg ? bR : bC;
    float* outb = isReg ? outR : outC;
    const int C9 = isReg ? 36 : 810;
    const int OC = isReg ? 4 : 90;
    const int n0b = isReg ? 0 : (yb - 1) * 96;

    int tid = threadIdx.x;
    int m0 = mx * 64;
    int lvl, base; lvl_of(m0, lvl, base);
    int logW = 6 - lvl, W = 1 << logW, HH = W * W, log2HH = 2 * logW;
    int pl0 = m0 - base;
    int lane = tid & 63, l15 = lane & 15, g = (lane >> 4) & 3;
    int wave = tid >> 6, wm = wave & 1, wn = wave >> 1;
    int ym[2], xm[2];
    const ushort* pbase[2];
#pragma unroll
    for (int mf = 0; mf < 2; ++mf) {
        int pl = pl0 + wm * 32 + mf * 16 + l15;
        int pp = pl & (HH - 1);
        ym[mf] = pp >> logW; xm[mf] = pp & (W - 1);
        pbase[mf] = in + (size_t)(base + pl) * 96 + g * 8;
    }
    const ushort* zbg = zb + g * 8;
    int fragoff = (g * 96 + wn * 48 + l15) * 8;

    auto stage = [&](int tap) {
        const ushort* src = Bg + tap * BSLAB;
        ushort* dst = (ushort*)Bs[tap & 1];
#pragma unroll
        for (int it = 0; it < 5; ++it) {
            int c = tid + it * 256;
            if (c < 1152) gld_lds16(src + (size_t)c * 8, dst + (size_t)c * 8);
        }
    };

    floatx4 acc[2][3];
#pragma unroll
    for (int aa = 0; aa < 2; ++aa)
#pragma unroll
        for (int bb = 0; bb < 3; ++bb) acc[aa][bb] = (floatx4){0.f, 0.f, 0.f, 0.f};

    stage(0);
    __syncthreads();
#pragma unroll
    for (int tap = 0; tap < 9; ++tap) {
        if (tap < 8) stage(tap + 1);
        const ushort* Bb = (const ushort*)Bs[tap & 1];
        const int dy = tap / 3 - 1, dx = tap % 3 - 1;
        int off96 = (dy * W + dx) * 96;
        const ushort* ap[2];
#pragma unroll
        for (int mf = 0; mf < 2; ++mf) {
            bool pred = ((unsigned)(ym[mf] + dy) < (unsigned)W) &&
                        ((unsigned)(xm[mf] + dx) < (unsigned)W);
            ap[mf] = pred ? (pbase[mf] + off96) : zbg;
        }
#pragma unroll
        for (int ks = 0; ks < 3; ++ks) {
            short8 a0 = *(const short8*)(ap[0] + ks * 32);
            short8 a1 = *(const short8*)(ap[1] + ks * 32);
            const ushort* bb = Bb + ks * 3072 + fragoff;
#pragma unroll
            for (int nf = 0; nf < 3; ++nf) {
                short8 b = *(const short8*)(bb + nf * 128);
                acc[0][nf] = __builtin_amdgcn_mfma_f32_16x16x32_bf16(a0, b, acc[0][nf], 0, 0, 0);
                acc[1][nf] = __builtin_amdgcn_mfma_f32_16x16x32_bf16(a1, b, acc[1][nf], 0, 0, 0);
            }
        }
        __syncthreads();
    }
#pragma unroll
    for (int nf = 0; nf < 3; ++nf) {
        int c = n0b + wn * 48 + nf * 16 + l15;
        if (c >= C9) continue;
        float bcv = bias[c];
        int a = c / OC, kk = c - a * OC;
#pragma unroll
        for (int mf = 0; mf < 2; ++mf)
#pragma unroll
            for (int r = 0; r < 4; ++r) {
                int pl = pl0 + wm * 32 + mf * 16 + g * 4 + r;
                int n = pl >> log2HH, pp = pl & (HH - 1);
                float v = acc[mf][nf][r] + bcv;
                if (!isReg) v = 1.f / (1.f + expf(-v));
                outb[((size_t)n * 49104 + LOFFc[lvl] + (size_t)pp * 9 + a) * OC + kk] = v;
            }
    }
}

// ---------------------------------------------------------------------------
// anchors + zero-buffer init (zb: 96 ushorts = 48 uints)
__global__ void anchors_k(float* __restrict__ out, ushort* __restrict__ zb) {
    int idx = blockIdx.x * blockDim.x + threadIdx.x;
    if (idx < 48) ((unsigned int*)zb)[idx] = 0u;
    if (idx >= 49104) return;
    const int offs[6] = {0, 36864, 46080, 48384, 48960, 49104};
    int l = 0;
    while (idx >= offs[l + 1]) ++l;
    int j = idx - offs[l];
    int a = j % 9;
    int p = j / 9;
    int fs = 64 >> l;
    int stride = 8 << l;
    float size = (float)(32 << l);
    int ix = p % fs, iy = p / fs;
    float cx = (ix + 0.5f) * (float)stride;
    float cy = (iy + 0.5f) * (float)stride;
    const float scl[3] = {1.0f, 1.2599210498948732f, 1.5874010519681994f};
    const float sqr[3] = {0.7071067811865476f, 1.0f, 1.4142135623730951f};
    int r = a / 3, s = a % 3;
    float w = size * scl[s] / sqr[r];
    float h = size * scl[s] * sqr[r];
    float* o = out + (size_t)idx * 4;
    o[0] = cx - 0.5f * w;
    o[1] = cy - 0.5f * h;
    o[2] = cx + 0.5f * w;
    o[3] = cy + 0.5f * h;
}

// ---------------------------------------------------------------------------

extern "C" void kernel_launch(void* const* d_in, const int* in_sizes, int n_in,
                              void* d_out, int out_size, void* d_ws, size_t ws_size,
                              hipStream_t stream) {
    const float* c_in[5]  = {(const float*)d_in[0],  (const float*)d_in[3],
                             (const float*)d_in[6],  (const float*)d_in[9],
                             (const float*)d_in[12]};
    const float* lat_w[5] = {(const float*)d_in[1],  (const float*)d_in[4],
                             (const float*)d_in[7],  (const float*)d_in[10],
                             (const float*)d_in[13]};
    const float* lat_b[5] = {(const float*)d_in[2],  (const float*)d_in[5],
                             (const float*)d_in[8],  (const float*)d_in[11],
                             (const float*)d_in[14]};
    const float* bif_dw  = (const float*)d_in[15];
    const float* bif_pw  = (const float*)d_in[16];
    const float* bif_pb  = (const float*)d_in[17];
    const float* bif_fw2 = (const float*)d_in[18];
    const float* bif_fw3 = (const float*)d_in[19];
    const float* reg_tw  = (const float*)d_in[20];
    const float* reg_tb  = (const float*)d_in[21];
    const float* reg_ow  = (const float*)d_in[22];
    const float* reg_ob  = (const float*)d_in[23];
    const float* cls_tw  = (const float*)d_in[24];
    const float* cls_tb  = (const float*)d_in[25];
    const float* cls_ow  = (const float*)d_in[26];
    const float* cls_ob  = (const float*)d_in[27];

    const int ROFF[5] = {0, 16384, 20480, 21504, 21760};
    const int ML[5]   = {16384, 4096, 1024, 256, 64};
    const size_t CONC = (size_t)CONC_ROWS * 96;

    ushort* ws = (ushort*)d_ws;
    size_t off = 0;
    ushort* CA = ws + off; off += CONC;
    ushort* CB = ws + off; off += CONC;
    ushort* T4 = ws + off; off += (size_t)4096 * 96;
    ushort* T5 = ws + off; off += (size_t)1024 * 96;
    ushort* T6 = ws + off; off += (size_t)256 * 96;
    ushort* HXR0 = ws + off; off += CONC;
    ushort* HXR1 = ws + off; off += CONC;
    ushort* HXC0 = ws + off; off += CONC;
    ushort* HXC1 = ws + off; off += CONC;
    ushort* BP_PW  = ws + off; off += (size_t)24 * BSLAB;
    ushort* BP_TW  = ws + off; off += (size_t)8 * 82944;
    ushort* BP_RO  = ws + off; off += (size_t)82944;
    ushort* BP_CO  = ws + off; off += (size_t)746496;
    ushort* BP_LAT = ws + off; off += (size_t)76800;
    ushort* ZB     = ws + off; off += 96;
    (void)ws_size; (void)n_in; (void)in_sizes; (void)out_size;

    // ---- merged packing (1 dispatch) ----
    pack_all_k<<<cdiv(1790976, TPB), TPB, 0, stream>>>(
        bif_pw, reg_tw, cls_tw, reg_ow, cls_ow,
        lat_w[0], lat_w[1], lat_w[2], lat_w[3], lat_w[4],
        BP_PW, BP_TW, BP_RO, BP_CO, BP_LAT);

    // ---- anchors + zero buffer ----
    float* cls_base = (float*)d_out;
    float* reg_base = cls_base + (size_t)4 * 49104 * 90;
    float* anc_base = reg_base + (size_t)4 * 49104 * 4;
    anchors_k<<<cdiv(49104, TPB), TPB, 0, stream>>>(anc_base, ZB);

    // ---- laterals (1 dispatch) ----
    lateral_all_k<<<341, 256, 0, stream>>>(
        c_in[0], c_in[1], c_in[2], c_in[3], c_in[4],
        lat_b[0], lat_b[1], lat_b[2], lat_b[3], lat_b[4], BP_LAT, CA);

    // ---- BiFPN: 8 fused sep-conv steps per stage ----
    ushort* cur = CA; ushort* nxt = CB;
    for (int s = 0; s < 3; ++s) {
        const float* dws = bif_dw + (size_t)s * 8 * 792;
        const float* pbs = bif_pb + (size_t)s * 8 * 88;
        const float* f2  = bif_fw2 + (size_t)s * 10;
        const float* f3  = bif_fw3 + (size_t)s * 9;
        auto LP = [&](ushort* buf, int l) { return buf + (size_t)ROFF[l] * 96; };
        auto BPW = [&](int ci) { return BP_PW + (size_t)(s * 8 + ci) * BSLAB; };

        sepconv_k<0><<<ML[3] / 64, 256, 0, stream>>>(
            LP(cur, 3), LP(cur, 4), nullptr, f2 + 0, dws + 0 * 792, BPW(0), pbs + 0 * 88, T6, 3);
        sepconv_k<0><<<ML[2] / 64, 256, 0, stream>>>(
            LP(cur, 2), T6, nullptr, f2 + 2, dws + 1 * 792, BPW(1), pbs + 1 * 88, T5, 4);
        sepconv_k<0><<<ML[1] / 64, 256, 0, stream>>>(
            LP(cur, 1), T5, nullptr, f2 + 4, dws + 2 * 792, BPW(2), pbs + 2 * 88, T4, 5);
        sepconv_k<0><<<ML[0] / 64, 256, 0, stream>>>(
            LP(cur, 0), T4, nullptr, f2 + 6, dws + 3 * 792, BPW(3), pbs + 3 * 88, LP(nxt, 0), 6);
        sepconv_k<2><<<ML[1] / 64, 256, 0, stream>>>(
            LP(cur, 1), T4, LP(nxt, 0), f3 + 0, dws + 4 * 792, BPW(4), pbs + 4 * 88, LP(nxt, 1), 5);
        sepconv_k<2><<<ML[2] / 64, 256, 0, stream>>>(
            LP(cur, 2), T5, LP(nxt, 1), f3 + 3, dws + 5 * 792, BPW(5), pbs + 5 * 88, LP(nxt, 2), 4);
        sepconv_k<2><<<ML[3] / 64, 256, 0, stream>>>(
            LP(cur, 3), T6, LP(nxt, 2), f3 + 6, dws + 6 * 792, BPW(6), pbs + 6 * 88, LP(nxt, 3), 3);
        sepconv_k<1><<<ML[4] / 64, 256, 0, stream>>>(
            LP(cur, 4), LP(nxt, 3), nullptr, f2 + 8, dws + 7 * 792, BPW(7), pbs + 7 * 88, LP(nxt, 4), 2);

        ushort* tp = cur; cur = nxt; nxt = tp;
    }

    // ---- heads: pipelined towers, then fused output convs ----
    const int GB = CONC_ROWS / 64;  // 341
    ushort* hxr[2] = {HXR0, HXR1};
    ushort* hxc[2] = {HXC0, HXC1};
    const ushort* xr = cur;
    const ushort* xc = cur;
    for (int i = 0; i < 4; ++i) {
        tower_pipe_k<<<dim3(GB, 2), 256, 0, stream>>>(
            xr, xc, BP_TW + (size_t)i * 82944, BP_TW + (size_t)(4 + i) * 82944,
            reg_tb + i * 88, cls_tb + i * 88, hxr[i & 1], hxc[i & 1], ZB);
        xr = hxr[i & 1]; xc = hxc[i & 1];
    }
    heads_pipe_k<<<3440, 256, 0, stream>>>(
        xr, xc, BP_RO, BP_CO, reg_ob, cls_ob, reg_base, cls_base, ZB);
}